// Round 2
// baseline (98.400 us; speedup 1.0000x reference)
//
#include <hip/hip_runtime.h>

// LIF constants (fp32): DT=1e-3, TAU_MEM_INV=200 -> v_decayed = v + 0.2*(i - v)
//                       TAU_SYN_INV=400 -> i_decayed = 0.6*i
// z = heaviside(v_decayed - 1) = (v_decayed > 1)   [exact: Sterbenz for a in [0.5,2],
//                                                    and a-1 >= 1 > 0 for a > 2]
#define VM_K 0.2f
#define SYN_DECAY 0.6f

__global__ __launch_bounds__(256) void lif_scan_kernel(
    const float* __restrict__ x, float* __restrict__ out, int N, int T)
{
    int idx = blockIdx.x * blockDim.x + threadIdx.x;
    if (idx >= N) return;

    float v1 = 0.f, i1 = 0.f, v2 = 0.f, i2 = 0.f;

    const float* xp = x + idx;
    float* op = out + idx;

#pragma unroll 8
    for (int t = 0; t < T; ++t) {
        float xt = __builtin_nontemporal_load(&xp[(size_t)t * N]);

        // layer 1
        float v1d = v1 + VM_K * (i1 - v1);
        float z1  = (v1d > 1.0f) ? 1.f : 0.f;
        v1 = (v1d > 1.0f) ? 0.f : v1d;
        i1 = SYN_DECAY * i1 + xt;

        // layer 2 (input = z1)
        float v2d = v2 + VM_K * (i2 - v2);
        float z2  = (v2d > 1.0f) ? 1.f : 0.f;
        v2 = (v2d > 1.0f) ? 0.f : v2d;
        i2 = SYN_DECAY * i2 + z1;

        __builtin_nontemporal_store(z2, &op[(size_t)t * N]);
    }
}

extern "C" void kernel_launch(void* const* d_in, const int* in_sizes, int n_in,
                              void* d_out, int out_size, void* d_ws, size_t ws_size,
                              hipStream_t stream) {
    const float* x = (const float*)d_in[0];
    float* out = (float*)d_out;

    // x: [T=256, B=16, H=128, W=128] fp32
    const int T = 256;
    const int N = in_sizes[0] / T;   // 262144 spatial elements

    const int block = 256;
    const int grid = (N + block - 1) / block;  // 1024 blocks -> 4 waves/SIMD

    lif_scan_kernel<<<grid, block, 0, stream>>>(x, out, N, T);
}